// Round 3
// baseline (358.239 us; speedup 1.0000x reference)
//
#include <hip/hip_runtime.h>

// SmoothMaxPool3D: out = T * logsumexp(window / T), window 2x2x2, stride 2.
// x: [8, 32, 64, 64, 64] f32 contiguous -> out: [8, 32, 32, 32, 32] f32.
// Memory-bound: 256 MiB in + 32 MiB out, every input element read exactly once.

#define INV_T_LOG2E 144.26950408889634f   // (1/T) * log2(e) = 100 * 1.4426950409
#define T_LN2       0.006931471805599453f // T * ln(2)

__device__ __forceinline__ float smax8(float a0, float a1, float a2, float a3,
                                       float a4, float a5, float a6, float a7,
                                       float* mout) {
    float m = fmaxf(fmaxf(fmaxf(a0, a1), fmaxf(a2, a3)),
                    fmaxf(fmaxf(a4, a5), fmaxf(a6, a7)));
    float s = __builtin_amdgcn_exp2f((a0 - m) * INV_T_LOG2E)
            + __builtin_amdgcn_exp2f((a1 - m) * INV_T_LOG2E)
            + __builtin_amdgcn_exp2f((a2 - m) * INV_T_LOG2E)
            + __builtin_amdgcn_exp2f((a3 - m) * INV_T_LOG2E)
            + __builtin_amdgcn_exp2f((a4 - m) * INV_T_LOG2E)
            + __builtin_amdgcn_exp2f((a5 - m) * INV_T_LOG2E)
            + __builtin_amdgcn_exp2f((a6 - m) * INV_T_LOG2E)
            + __builtin_amdgcn_exp2f((a7 - m) * INV_T_LOG2E);
    *mout = m;
    return s;
}

__global__ __launch_bounds__(256) void smooth_maxpool3d_kernel(
    const float* __restrict__ x, float* __restrict__ out) {
    // Each thread: 2 adjacent outputs along W (shares the 4 input rows).
    // Work decomposition (all powers of two -> shift/mask decode):
    //   ox2 : 16 pairs along ow=32
    //   oy  : 32
    //   oz  : 32
    //   bc  : 256 (b*c)
    const int tid = blockIdx.x * 256 + threadIdx.x;  // 0 .. 4194303 exactly

    const int ox2 = tid & 15;
    const int oy  = (tid >> 4) & 31;
    const int oz  = (tid >> 9) & 31;
    const int bc  = tid >> 14;

    // Input base: bc*64^3 + (2*oz)*64*64 + (2*oy)*64 + 4*ox2  (elements)
    const int in_base = (bc << 18) + (oz << 13) + (oy << 7) + (ox2 << 2);

    const float4 r00 = *reinterpret_cast<const float4*>(x + in_base);            // z0,y0
    const float4 r01 = *reinterpret_cast<const float4*>(x + in_base + 64);       // z0,y1
    const float4 r10 = *reinterpret_cast<const float4*>(x + in_base + 4096);     // z1,y0
    const float4 r11 = *reinterpret_cast<const float4*>(x + in_base + 4096+64);  // z1,y1

    float m0, m1;
    const float s0 = smax8(r00.x, r00.y, r01.x, r01.y, r10.x, r10.y, r11.x, r11.y, &m0);
    const float s1 = smax8(r00.z, r00.w, r01.z, r01.w, r10.z, r10.w, r11.z, r11.w, &m1);

    float2 res;
    res.x = fmaf(T_LN2, __builtin_amdgcn_logf(s0), m0);
    res.y = fmaf(T_LN2, __builtin_amdgcn_logf(s1), m1);

    // Output: bc*32^3 + oz*32^2 + oy*32 + ox2*2
    const int out_idx = (bc << 15) + (oz << 10) + (oy << 5) + (ox2 << 1);
    *reinterpret_cast<float2*>(out + out_idx) = res;
}

extern "C" void kernel_launch(void* const* d_in, const int* in_sizes, int n_in,
                              void* d_out, int out_size, void* d_ws, size_t ws_size,
                              hipStream_t stream) {
    const float* x = (const float*)d_in[0];
    float* out = (float*)d_out;
    // total threads = 8*32*32*32*16 = 4,194,304 = 16384 blocks x 256
    smooth_maxpool3d_kernel<<<16384, 256, 0, stream>>>(x, out);
}

// Round 10
// 346.854 us; speedup vs baseline: 1.0328x; 1.0328x over previous
//
#include <hip/hip_runtime.h>

// SmoothMaxPool3D: out = T * logsumexp(window / T), window 2x2x2, stride 2.
// x: [8, 32, 64, 64, 64] f32 contiguous -> out: [8, 32, 32, 32, 32] f32.
// Memory-bound: 256 MiB read once + 32 MiB written once -> ~48 us floor @ 6.3 TB/s.
// R5: same as R4 plan but with clang native vectors (ext_vector_type) because
//     __builtin_nontemporal_* rejects HIP_vector_type (float4 is a class).

#define INV_T_LOG2E 144.26950408889634f   // (1/T) * log2(e) = 100 * 1.4426950409
#define T_LN2       0.006931471805599453f // T * ln(2)

typedef float f32x4 __attribute__((ext_vector_type(4)));

__device__ __forceinline__ float smax_pair(float a0, float a1, float a2, float a3,
                                           float a4, float a5, float a6, float a7) {
    float m = fmaxf(fmaxf(fmaxf(a0, a1), fmaxf(a2, a3)),
                    fmaxf(fmaxf(a4, a5), fmaxf(a6, a7)));
    float s = __builtin_amdgcn_exp2f((a0 - m) * INV_T_LOG2E)
            + __builtin_amdgcn_exp2f((a1 - m) * INV_T_LOG2E)
            + __builtin_amdgcn_exp2f((a2 - m) * INV_T_LOG2E)
            + __builtin_amdgcn_exp2f((a3 - m) * INV_T_LOG2E)
            + __builtin_amdgcn_exp2f((a4 - m) * INV_T_LOG2E)
            + __builtin_amdgcn_exp2f((a5 - m) * INV_T_LOG2E)
            + __builtin_amdgcn_exp2f((a6 - m) * INV_T_LOG2E)
            + __builtin_amdgcn_exp2f((a7 - m) * INV_T_LOG2E);
    return fmaf(T_LN2, __builtin_amdgcn_logf(s), m);
}

__global__ __launch_bounds__(256) void smooth_maxpool3d_kernel(
    const float* __restrict__ x, float* __restrict__ out) {
    // Each thread: 4 adjacent outputs along W (8 input floats x 4 rows = 128B).
    //   ox4 : 8 quads along ow=32
    //   oy  : 32
    //   oz  : 32
    //   bc  : 256 (b*c)
    const int tid = blockIdx.x * 256 + threadIdx.x;  // 0 .. 2097151

    const int ox4 = tid & 7;
    const int oy  = (tid >> 3) & 31;
    const int oz  = (tid >> 8) & 31;
    const int bc  = tid >> 13;

    // Input base (elements): bc*64^3 + (2*oz)*4096 + (2*oy)*64 + 8*ox4
    const int in_base = (bc << 18) + (oz << 13) + (oy << 7) + (ox4 << 3);
    const f32x4* p = reinterpret_cast<const f32x4*>(x + in_base);

    // 8 independent 16B loads, all issued before first use (MLP).
    // rows: z0y0 @ +0, z0y1 @ +64 fl (=16 f32x4), z1y0 @ +4096 fl (=1024),
    //       z1y1 @ +4160 fl (=1040); each row = 2 consecutive f32x4.
    const f32x4 a0 = __builtin_nontemporal_load(p);          // z0 y0 w[0:4)
    const f32x4 a1 = __builtin_nontemporal_load(p + 1);      // z0 y0 w[4:8)
    const f32x4 b0 = __builtin_nontemporal_load(p + 16);     // z0 y1 w[0:4)
    const f32x4 b1 = __builtin_nontemporal_load(p + 17);     // z0 y1 w[4:8)
    const f32x4 c0 = __builtin_nontemporal_load(p + 1024);   // z1 y0 w[0:4)
    const f32x4 c1 = __builtin_nontemporal_load(p + 1025);   // z1 y0 w[4:8)
    const f32x4 d0 = __builtin_nontemporal_load(p + 1040);   // z1 y1 w[0:4)
    const f32x4 d1 = __builtin_nontemporal_load(p + 1041);   // z1 y1 w[4:8)

    f32x4 res;
    res.x = smax_pair(a0.x, a0.y, b0.x, b0.y, c0.x, c0.y, d0.x, d0.y);
    res.y = smax_pair(a0.z, a0.w, b0.z, b0.w, c0.z, c0.w, d0.z, d0.w);
    res.z = smax_pair(a1.x, a1.y, b1.x, b1.y, c1.x, c1.y, d1.x, d1.y);
    res.w = smax_pair(a1.z, a1.w, b1.z, b1.w, c1.z, c1.w, d1.z, d1.w);

    // Output: bc*32^3 + oz*1024 + oy*32 + ox4*4
    const int out_idx = (bc << 15) + (oz << 10) + (oy << 5) + (ox4 << 2);
    __builtin_nontemporal_store(res, reinterpret_cast<f32x4*>(out + out_idx));
}

extern "C" void kernel_launch(void* const* d_in, const int* in_sizes, int n_in,
                              void* d_out, int out_size, void* d_ws, size_t ws_size,
                              hipStream_t stream) {
    const float* x = (const float*)d_in[0];
    float* out = (float*)d_out;
    // total threads = 8*32*32*32*8 = 2,097,152 = 8192 blocks x 256
    smooth_maxpool3d_kernel<<<8192, 256, 0, stream>>>(x, out);
}